// Round 1
// baseline (381.574 us; speedup 1.0000x reference)
//
#include <hip/hip_runtime.h>
#include <stdint.h>

#define DIM 64
#define GB 128          // nodes per dst-bucket (NB = ceil(N/GB) must be <= 1024)
#define GSH 7
#define CH 8192         // edges per partition block
#define TB1 512
#define SCAN_TILE 1024  // elements per scan block (256 threads x 4)

// bf16 helpers: RNE pack, shift-unpack
__device__ __forceinline__ unsigned bf16rne(float f) {
    unsigned u = __float_as_uint(f);
    return (u + 0x7FFFu + ((u >> 16) & 1u)) >> 16;
}
__device__ __forceinline__ unsigned pack2(float lo, float hi) {
    return bf16rne(lo) | (bf16rne(hi) << 16);
}
#define UNPK(u, lo, hi) { lo = __uint_as_float((u) << 16); hi = __uint_as_float((u) & 0xFFFF0000u); }

// ---- degree counting: plain device-scope atomics (replaces hist+merge) --
__global__ void __launch_bounds__(256)
deg_kernel(const int* __restrict__ src, const int* __restrict__ dst,
           int* __restrict__ indeg, int* __restrict__ outdeg, int E) {
    const int i0 = (blockIdx.x * blockDim.x + threadIdx.x) * 4;
    if (i0 + 3 < E) {
        int4 ss = *(const int4*)(src + i0);
        int4 tt = *(const int4*)(dst + i0);
        atomicAdd(&outdeg[ss.x], 1); atomicAdd(&outdeg[ss.y], 1);
        atomicAdd(&outdeg[ss.z], 1); atomicAdd(&outdeg[ss.w], 1);
        atomicAdd(&indeg[tt.x], 1);  atomicAdd(&indeg[tt.y], 1);
        atomicAdd(&indeg[tt.z], 1);  atomicAdd(&indeg[tt.w], 1);
    } else {
        for (int i = i0; i < E; ++i) {
            atomicAdd(&outdeg[src[i]], 1);
            atomicAdd(&indeg[dst[i]], 1);
        }
    }
}

// ---- node-offset scan (3 phases, unchanged) -----------------------------

__global__ void __launch_bounds__(256)
scan_partial(const int* __restrict__ indeg, int* __restrict__ partial, int n) {
    __shared__ int wsum[4];
    const int tid = threadIdx.x;
    const int base = blockIdx.x * SCAN_TILE + tid * 4;
    int s = 0;
    if (base + 3 < n) {
        int4 v = *(const int4*)(indeg + base);
        s = v.x + v.y + v.z + v.w;
    } else {
        for (int i = 0; i < 4; ++i) if (base + i < n) s += indeg[base + i];
    }
    for (int off = 32; off > 0; off >>= 1) s += __shfl_down(s, off, 64);
    const int lane = tid & 63, wid = tid >> 6;
    if (lane == 0) wsum[wid] = s;
    __syncthreads();
    if (tid == 0) partial[blockIdx.x] = wsum[0] + wsum[1] + wsum[2] + wsum[3];
}

__global__ void scan_blocksums(int* __restrict__ partial, int* __restrict__ offsets,
                               int nblocks, int n) {
    __shared__ int buf[1024];
    const int t = threadIdx.x;
    int v = (t < nblocks) ? partial[t] : 0;
    buf[t] = v;
    __syncthreads();
    for (int off = 1; off < 1024; off <<= 1) {
        int add = (t >= off) ? buf[t - off] : 0;
        __syncthreads();
        buf[t] += add;
        __syncthreads();
    }
    if (t < nblocks) partial[t] = buf[t] - v;
    if (t == 1023) offsets[n] = buf[1023];
}

__global__ void __launch_bounds__(256)
scan_final(const int* __restrict__ indeg, const int* __restrict__ partial,
           int* __restrict__ offsets, int n) {
    __shared__ int wpre[4];
    const int tid = threadIdx.x;
    const int base = blockIdx.x * SCAN_TILE + tid * 4;
    int v0 = 0, v1 = 0, v2 = 0, v3 = 0;
    if (base + 3 < n) {
        int4 v = *(const int4*)(indeg + base);
        v0 = v.x; v1 = v.y; v2 = v.z; v3 = v.w;
    } else {
        if (base + 0 < n) v0 = indeg[base + 0];
        if (base + 1 < n) v1 = indeg[base + 1];
        if (base + 2 < n) v2 = indeg[base + 2];
        if (base + 3 < n) v3 = indeg[base + 3];
    }
    const int s = v0 + v1 + v2 + v3;
    int inc = s;
    const int lane = tid & 63, wid = tid >> 6;
    for (int off = 1; off < 64; off <<= 1) {
        int t = __shfl_up(inc, off, 64);
        if (lane >= off) inc += t;
    }
    if (lane == 63) wpre[wid] = inc;
    __syncthreads();
    if (tid == 0) {
        int r = 0;
        for (int w = 0; w < 4; ++w) { int t = wpre[w]; wpre[w] = r; r += t; }
    }
    __syncthreads();
    int run = (inc - s) + wpre[wid] + partial[blockIdx.x];
    if (base + 0 < n) { offsets[base + 0] = run; run += v0; }
    if (base + 1 < n) { offsets[base + 1] = run; run += v1; }
    if (base + 2 < n) { offsets[base + 2] = run; run += v2; }
    if (base + 3 < n) { offsets[base + 3] = run; run += v3; }
}

// dis = rsqrt(outdeg+1); bucket write cursors start at offsets[bucket*GB]
__global__ void __launch_bounds__(256)
prep_kernel(const int* __restrict__ outdeg, const int* __restrict__ offsets,
            float* __restrict__ dis, int* __restrict__ cursor, int N, int NB) {
    const int i = blockIdx.x * blockDim.x + threadIdx.x;
    if (i < N) dis[i] = rsqrtf((float)outdeg[i] + 1.0f);
    if (i < NB) cursor[i] = offsets[i << GSH];
}

// ---- phase 1: partition edges into dst-bucket-major staging -------------
// Each block: LDS histogram of its CH edges over NB buckets, one global
// atomicAdd per (block,bucket) to reserve a contiguous run, then write
// records (src | tlocal<<20, w) grouped per bucket. Runs avg ~10 records
// (84 B) so staged lines are mostly single-owner -> L2 assembles them.
__global__ void __launch_bounds__(TB1)
part_kernel(const int* __restrict__ src, const int* __restrict__ dst,
            const float* __restrict__ ew, const float* __restrict__ dis,
            int* __restrict__ cursor, int2* __restrict__ staged, int E, int NB) {
    __shared__ int h[1024];
    const int tid = threadIdx.x;
    const int e0 = blockIdx.x * CH;
    const int e1 = min(e0 + CH, E);
    for (int j = tid; j < NB; j += TB1) h[j] = 0;
    __syncthreads();
    // pass A: histogram dst buckets, keep dst values in registers
    int4 d[4];
    int ngrp = 0;
    for (int i = e0 + tid * 4, k = 0; i < e1; i += TB1 * 4, ++k) {
        int4 t;
        if (i + 3 < e1) t = *(const int4*)(dst + i);
        else {
            t.x = dst[i];
            t.y = (i + 1 < e1) ? dst[i + 1] : -1;
            t.z = (i + 2 < e1) ? dst[i + 2] : -1;
            t.w = (i + 3 < e1) ? dst[i + 3] : -1;
        }
        d[k] = t;
        if (t.x >= 0) atomicAdd(&h[t.x >> GSH], 1);
        if (t.y >= 0) atomicAdd(&h[t.y >> GSH], 1);
        if (t.z >= 0) atomicAdd(&h[t.z >> GSH], 1);
        if (t.w >= 0) atomicAdd(&h[t.w >> GSH], 1);
        ngrp = k + 1;
    }
    __syncthreads();
    // reserve contiguous runs in the bucket-major staging array
    for (int j = tid; j < NB; j += TB1) {
        int c = h[j];
        h[j] = c ? atomicAdd(&cursor[j], c) : 0;
    }
    __syncthreads();
    // pass B: compute w, write packed records into reserved runs
    for (int i = e0 + tid * 4, k = 0; k < ngrp; i += TB1 * 4, ++k) {
        int4 t = d[k];
        int4 ss = make_int4(0, 0, 0, 0);
        float4 ww = make_float4(0.f, 0.f, 0.f, 0.f);
        if (i + 3 < e1) { ss = *(const int4*)(src + i); ww = *(const float4*)(ew + i); }
        else {
            ss.x = src[i]; ww.x = ew[i];
            if (i + 1 < e1) { ss.y = src[i + 1]; ww.y = ew[i + 1]; }
            if (i + 2 < e1) { ss.z = src[i + 2]; ww.z = ew[i + 2]; }
            if (i + 3 < e1) { ss.w = src[i + 3]; ww.w = ew[i + 3]; }
        }
#define PART1(T, S, W) if ((T) >= 0) { \
        float w_ = dis[S] * (W) * dis[T]; \
        int pos_ = atomicAdd(&h[(T) >> GSH], 1); \
        staged[pos_] = make_int2((S) | (((T) & (GB - 1)) << 20), __float_as_int(w_)); }
        PART1(t.x, ss.x, ww.x)
        PART1(t.y, ss.y, ww.y)
        PART1(t.z, ss.z, ww.z)
        PART1(t.w, ss.w, ww.w)
#undef PART1
    }
}

// ---- phase 2: per-bucket placement into final CSR -----------------------
// One block owns one bucket: sequential read of its staged records, rank
// via LDS counters, write csr within a single ~16 KB region -> every csr
// line is written by exactly one block (no RFO thrash).
__global__ void __launch_bounds__(256)
place_kernel(const int2* __restrict__ staged, const int* __restrict__ offsets,
             int2* __restrict__ csr, int N) {
    __shared__ int offs[GB + 1];
    __shared__ int cnt[GB];
    const int n0 = blockIdx.x << GSH;
    const int nb = min(GB, N - n0);
    for (int j = threadIdx.x; j < nb + 1; j += 256) offs[j] = offsets[n0 + j];
    for (int j = threadIdx.x; j < GB; j += 256) cnt[j] = 0;
    __syncthreads();
    const int r0 = offs[0], r1 = offs[nb];
    for (int i = r0 + threadIdx.x; i < r1; i += 256) {
        int2 rec = staged[i];
        int tl = (rec.x >> 20) & (GB - 1);
        int s = rec.x & 0xFFFFF;
        int rank = atomicAdd(&cnt[tl], 1);
        csr[offs[tl] + rank] = make_int2(s, rec.y);
    }
}

// fp32 emb -> bf16 copy (one uint4 = 8 bf16 per thread)
__global__ void __launch_bounds__(256)
conv_kernel(const float4* __restrict__ in4, uint4* __restrict__ outb, int n8) {
    int i = blockIdx.x * blockDim.x + threadIdx.x;
    if (i >= n8) return;
    float4 a = in4[2 * i], b = in4[2 * i + 1];
    uint4 o;
    o.x = pack2(a.x, a.y); o.y = pack2(a.z, a.w);
    o.z = pack2(b.x, b.y); o.w = pack2(b.z, b.w);
    outb[i] = o;
}

// ---- propagation (unchanged) --------------------------------------------
// 8 nodes per wave: lane = (sub = lane>>3 -> node, fl = lane&7 -> 16B chunk
// = 8 bf16 of the 128B bf16 row). x8 unroll -> 64 row-gathers in flight.
__global__ void __launch_bounds__(256)
prop_kernel(const uint4* __restrict__ xg, const float4* __restrict__ selfF,
            uint4* __restrict__ xstore,
            const int* __restrict__ offsets, const int2* __restrict__ csr,
            const float* __restrict__ dis, int n) {
    const int lane = threadIdx.x & 63;
    const int fl  = lane & 7;
    const int sub = lane >> 3;
    const int wave = blockIdx.x * (blockDim.x >> 6) + (threadIdx.x >> 6);
    const int node = wave * 8 + sub;
    if (node >= n) return;

    const int beg = offsets[node];
    const int end = offsets[node + 1];
    const float d = dis[node];
    const float dd = d * d;   // self-loop: norm = dis[i]^2, weight 1

    float a0, a1, a2, a3, a4, a5, a6, a7;
    if (selfF) {
        float4 s0 = selfF[node * 16 + fl * 2];
        float4 s1 = selfF[node * 16 + fl * 2 + 1];
        a0 = dd * s0.x; a1 = dd * s0.y; a2 = dd * s0.z; a3 = dd * s0.w;
        a4 = dd * s1.x; a5 = dd * s1.y; a6 = dd * s1.z; a7 = dd * s1.w;
    } else {
        uint4 q = xg[(size_t)node * 8 + fl];
        float l, h;
        UNPK(q.x, l, h) a0 = dd * l; a1 = dd * h;
        UNPK(q.y, l, h) a2 = dd * l; a3 = dd * h;
        UNPK(q.z, l, h) a4 = dd * l; a5 = dd * h;
        UNPK(q.w, l, h) a6 = dd * l; a7 = dd * h;
    }

#define EDGE(E, Q) { float w_ = __int_as_float((E).y); float l, h; \
    UNPK((Q).x, l, h) a0 = fmaf(w_, l, a0); a1 = fmaf(w_, h, a1); \
    UNPK((Q).y, l, h) a2 = fmaf(w_, l, a2); a3 = fmaf(w_, h, a3); \
    UNPK((Q).z, l, h) a4 = fmaf(w_, l, a4); a5 = fmaf(w_, h, a5); \
    UNPK((Q).w, l, h) a6 = fmaf(w_, l, a6); a7 = fmaf(w_, h, a7); }

    int p = beg;
    for (; p + 8 <= end; p += 8) {
        int2 e0 = csr[p + 0], e1 = csr[p + 1], e2 = csr[p + 2], e3 = csr[p + 3];
        int2 e4 = csr[p + 4], e5 = csr[p + 5], e6 = csr[p + 6], e7 = csr[p + 7];
        uint4 q0 = xg[(size_t)e0.x * 8 + fl];
        uint4 q1 = xg[(size_t)e1.x * 8 + fl];
        uint4 q2 = xg[(size_t)e2.x * 8 + fl];
        uint4 q3 = xg[(size_t)e3.x * 8 + fl];
        uint4 q4 = xg[(size_t)e4.x * 8 + fl];
        uint4 q5 = xg[(size_t)e5.x * 8 + fl];
        uint4 q6 = xg[(size_t)e6.x * 8 + fl];
        uint4 q7 = xg[(size_t)e7.x * 8 + fl];
        EDGE(e0, q0) EDGE(e1, q1) EDGE(e2, q2) EDGE(e3, q3)
        EDGE(e4, q4) EDGE(e5, q5) EDGE(e6, q6) EDGE(e7, q7)
    }
    for (; p + 4 <= end; p += 4) {
        int2 e0 = csr[p + 0], e1 = csr[p + 1], e2 = csr[p + 2], e3 = csr[p + 3];
        uint4 q0 = xg[(size_t)e0.x * 8 + fl];
        uint4 q1 = xg[(size_t)e1.x * 8 + fl];
        uint4 q2 = xg[(size_t)e2.x * 8 + fl];
        uint4 q3 = xg[(size_t)e3.x * 8 + fl];
        EDGE(e0, q0) EDGE(e1, q1) EDGE(e2, q2) EDGE(e3, q3)
    }
    for (; p < end; ++p) {
        int2 e = csr[p];
        uint4 q = xg[(size_t)e.x * 8 + fl];
        EDGE(e, q)
    }
#undef EDGE

    uint4 o;
    o.x = pack2(a0, a1); o.y = pack2(a2, a3);
    o.z = pack2(a4, a5); o.w = pack2(a6, a7);
    xstore[(size_t)node * 8 + fl] = o;
}

// out = 0.25 * (emb + xa + xb + xc), pure streaming.
__global__ void __launch_bounds__(256)
combine_kernel(const float4* __restrict__ emb4, const uint4* __restrict__ xa,
               const uint4* __restrict__ xb, const uint4* __restrict__ xc,
               float4* __restrict__ out4, int n8) {
    int i = blockIdx.x * blockDim.x + threadIdx.x;
    if (i >= n8) return;
    float4 e0 = emb4[2 * i], e1 = emb4[2 * i + 1];
    uint4 qa = xa[i], qb = xb[i], qc = xc[i];
    float r[8] = { e0.x, e0.y, e0.z, e0.w, e1.x, e1.y, e1.z, e1.w };
    float l, h;
    UNPK(qa.x, l, h) r[0] += l; r[1] += h;
    UNPK(qa.y, l, h) r[2] += l; r[3] += h;
    UNPK(qa.z, l, h) r[4] += l; r[5] += h;
    UNPK(qa.w, l, h) r[6] += l; r[7] += h;
    UNPK(qb.x, l, h) r[0] += l; r[1] += h;
    UNPK(qb.y, l, h) r[2] += l; r[3] += h;
    UNPK(qb.z, l, h) r[4] += l; r[5] += h;
    UNPK(qb.w, l, h) r[6] += l; r[7] += h;
    UNPK(qc.x, l, h) r[0] += l; r[1] += h;
    UNPK(qc.y, l, h) r[2] += l; r[3] += h;
    UNPK(qc.z, l, h) r[4] += l; r[5] += h;
    UNPK(qc.w, l, h) r[6] += l; r[7] += h;
    out4[2 * i]     = make_float4(0.25f * r[0], 0.25f * r[1], 0.25f * r[2], 0.25f * r[3]);
    out4[2 * i + 1] = make_float4(0.25f * r[4], 0.25f * r[5], 0.25f * r[6], 0.25f * r[7]);
}

// ---- launch -------------------------------------------------------------

extern "C" void kernel_launch(void* const* d_in, const int* in_sizes, int n_in,
                              void* d_out, int out_size, void* d_ws, size_t ws_size,
                              hipStream_t stream) {
    const float* emb = (const float*)d_in[0];   // [N, 64] fp32
    const float* ew  = (const float*)d_in[1];   // [E] fp32
    const int*   ei  = (const int*)d_in[2];     // [2, E] int32
    const int E = in_sizes[2] / 2;
    const int N = in_sizes[0] / DIM;
    const int* src = ei;        // edge_index[0] = source j
    const int* dst = ei + E;    // edge_index[1] = target i
    float* out = (float*)d_out;

    const int NB = (N + GB - 1) >> GSH;            // dst buckets (782 @ N=100k)
    const int nscan = (N + SCAN_TILE - 1) / SCAN_TILE;

    // workspace (~66 MB). Alias: xb (bf16 12.8 MB) lives on staged (dead
    // after place_kernel; xb first written in prop L2).
    char* w = (char*)d_ws;
    size_t xSz = ((size_t)N * DIM * 2 + 255) & ~(size_t)255;   // 12.8 MB
    size_t sSz = ((size_t)E * 8 + 255) & ~(size_t)255;         // 12.8 MB
    size_t uSz = (sSz > xSz) ? sSz : xSz;
    int2* staged = (int2*)w;
    uint4* xb    = (uint4*)w; w += uSz;
    int2* csr    = (int2*)w; w += sSz;
    uint4* x0c   = (uint4*)w; w += xSz;   // bf16 emb copy
    uint4* xa    = (uint4*)w; w += xSz;   // bf16 layer-1 x
    uint4* xc    = (uint4*)w; w += xSz;   // bf16 layer-3 x
    int* indeg   = (int*)w; int* outdeg = indeg + N;
    w += ((size_t)2 * N * 4 + 255) & ~(size_t)255;
    int* offsets = (int*)w; w += ((size_t)(N + 1) * 4 + 255) & ~(size_t)255;
    float* dis   = (float*)w; w += ((size_t)N * 4 + 255) & ~(size_t)255;
    int* partial = (int*)w; w += 4096;
    int* cursor  = (int*)w; w += ((size_t)NB * 4 + 255) & ~(size_t)255;

    const int TB = 256;
    hipMemsetAsync(indeg, 0, (size_t)2 * N * 4, stream);

    const int e4 = (E + 3) / 4;
    deg_kernel<<<(e4 + TB - 1) / TB, TB, 0, stream>>>(src, dst, indeg, outdeg, E);
    scan_partial<<<nscan, TB, 0, stream>>>(indeg, partial, N);
    scan_blocksums<<<1, 1024, 0, stream>>>(partial, offsets, nscan, N);
    scan_final<<<nscan, TB, 0, stream>>>(indeg, partial, offsets, N);
    prep_kernel<<<(N + TB - 1) / TB, TB, 0, stream>>>(outdeg, offsets, dis, cursor, N, NB);
    part_kernel<<<(E + CH - 1) / CH, TB1, 0, stream>>>(src, dst, ew, dis, cursor,
                                                       staged, E, NB);
    place_kernel<<<NB, TB, 0, stream>>>(staged, offsets, csr, N);

    const int n8 = N * DIM / 8;
    conv_kernel<<<(n8 + TB - 1) / TB, TB, 0, stream>>>((const float4*)emb, x0c, n8);

    // 4 waves/block, 8 nodes/wave -> 32 nodes per block
    dim3 grid((N + 31) / 32), block(TB);
    prop_kernel<<<grid, block, 0, stream>>>(x0c, (const float4*)emb, xa,
                                            offsets, csr, dis, N);
    prop_kernel<<<grid, block, 0, stream>>>(xa, nullptr, xb,
                                            offsets, csr, dis, N);
    prop_kernel<<<grid, block, 0, stream>>>(xb, nullptr, xc,
                                            offsets, csr, dis, N);
    combine_kernel<<<(n8 + TB - 1) / TB, TB, 0, stream>>>((const float4*)emb, xa, xb, xc,
                                                          (float4*)out, n8);
}

// Round 2
// 284.627 us; speedup vs baseline: 1.3406x; 1.3406x over previous
//
#include <hip/hip_runtime.h>
#include <stdint.h>

#define DIM 64
#define GB 128          // nodes per dst-bucket (NB = ceil(N/GB) must be <= 1024)
#define GSH 7
#define CH 8192         // edges per partition block
#define TB1 512
#define BINS2 50000     // hist bins per range (u16-packed: 25000 words = 100 KB LDS)
#define RANGES 2        // ceil(100000 / 50000)
#define NSLICE 64       // edge slices for src hist
#define TBH 1024        // hist block size

// bf16 helpers: RNE pack, shift-unpack
__device__ __forceinline__ unsigned bf16rne(float f) {
    unsigned u = __float_as_uint(f);
    return (u + 0x7FFFu + ((u >> 16) & 1u)) >> 16;
}
__device__ __forceinline__ unsigned pack2(float lo, float hi) {
    return bf16rne(lo) | (bf16rne(hi) << 16);
}
#define UNPK(u, lo, hi) { lo = __uint_as_float((u) << 16); hi = __uint_as_float((u) & 0xFFFF0000u); }

// ---- outdeg histogram: u16-packed LDS counters, no global atomics -------
__global__ void __launch_bounds__(TBH)
hist_src_kernel(const int* __restrict__ src, unsigned short* __restrict__ partials,
                int E, int N, int Es) {
    __shared__ unsigned h32[BINS2 / 2];  // 100 KB
    const int b = blockIdx.x;
    const int r = b / NSLICE, s = b % NSLICE;
    const int base = r * BINS2;
    const int hi = min(base + BINS2, N);
    const int nbw = (hi - base + 1) >> 1;  // words (N, base even)
    for (int j = threadIdx.x; j < nbw; j += TBH) h32[j] = 0;
    __syncthreads();
    const int e0 = s * Es, e1 = min(e0 + Es, E);
#pragma unroll 4
    for (int i = e0 + threadIdx.x; i < e1; i += TBH) {
        unsigned j = (unsigned)(src[i] - base);
        if (j < (unsigned)BINS2) atomicAdd(&h32[j >> 1], 1u << ((j & 1) * 16));
    }
    __syncthreads();
    unsigned* part = (unsigned*)(partials + (size_t)s * N + base);
    for (int j = threadIdx.x; j < nbw; j += TBH) part[j] = h32[j];
}

// dis[i] = rsqrt(outdeg + 1)
__global__ void __launch_bounds__(256)
merge_dis_kernel(const unsigned short* __restrict__ partials, float* __restrict__ dis, int N) {
    const int i = blockIdx.x * blockDim.x + threadIdx.x;
    if (i >= N) return;
    int od = 0;
    for (int s = 0; s < NSLICE; ++s) od += partials[(size_t)s * N + i];
    dis[i] = rsqrtf((float)od + 1.0f);
}

// ---- dst-bucket totals: LDS hist + coalesced global adds ----------------
__global__ void __launch_bounds__(256)
bucket_cnt_kernel(const int* __restrict__ dst, int* __restrict__ bcnt, int E, int NB) {
    __shared__ int h[1024];
    for (int j = threadIdx.x; j < NB; j += 256) h[j] = 0;
    __syncthreads();
    const int chunk = (E + gridDim.x - 1) / gridDim.x;
    const int e0 = blockIdx.x * chunk, e1 = min(e0 + chunk, E);
    for (int i = e0 + threadIdx.x; i < e1; i += 256)
        atomicAdd(&h[((unsigned)dst[i]) >> GSH], 1);
    __syncthreads();
    for (int j = threadIdx.x; j < NB; j += 256)
        if (h[j]) atomicAdd(&bcnt[j], h[j]);
}

// single block: exclusive scan of bucket counts -> bases + write cursors
__global__ void scan_buckets(const int* __restrict__ bcnt, int* __restrict__ bucket_base,
                             int* __restrict__ cursor, int* __restrict__ offsets,
                             int NB, int N) {
    __shared__ int buf[1024];
    const int t = threadIdx.x;
    int v = (t < NB) ? bcnt[t] : 0;
    buf[t] = v;
    __syncthreads();
    for (int off = 1; off < 1024; off <<= 1) {
        int add = (t >= off) ? buf[t - off] : 0;
        __syncthreads();
        buf[t] += add;
        __syncthreads();
    }
    if (t < NB) { bucket_base[t] = buf[t] - v; cursor[t] = buf[t] - v; }
    if (t == NB - 1) { bucket_base[NB] = buf[t]; offsets[N] = buf[t]; }
}

// ---- phase 1: partition edges into dst-bucket-major staging -------------
// Each block: LDS histogram of its CH edges over NB buckets, one global
// atomicAdd per (block,bucket) to reserve a contiguous run, then write
// records (src | tlocal<<20, w) grouped per bucket.
__global__ void __launch_bounds__(TB1)
part_kernel(const int* __restrict__ src, const int* __restrict__ dst,
            const float* __restrict__ ew, const float* __restrict__ dis,
            int* __restrict__ cursor, int2* __restrict__ staged, int E, int NB) {
    __shared__ int h[1024];
    const int tid = threadIdx.x;
    const int e0 = blockIdx.x * CH;
    const int e1 = min(e0 + CH, E);
    for (int j = tid; j < NB; j += TB1) h[j] = 0;
    __syncthreads();
    // pass A: histogram dst buckets, keep dst values in registers
    int4 d[4];
    int ngrp = 0;
    for (int i = e0 + tid * 4, k = 0; i < e1; i += TB1 * 4, ++k) {
        int4 t;
        if (i + 3 < e1) t = *(const int4*)(dst + i);
        else {
            t.x = dst[i];
            t.y = (i + 1 < e1) ? dst[i + 1] : -1;
            t.z = (i + 2 < e1) ? dst[i + 2] : -1;
            t.w = (i + 3 < e1) ? dst[i + 3] : -1;
        }
        d[k] = t;
        if (t.x >= 0) atomicAdd(&h[t.x >> GSH], 1);
        if (t.y >= 0) atomicAdd(&h[t.y >> GSH], 1);
        if (t.z >= 0) atomicAdd(&h[t.z >> GSH], 1);
        if (t.w >= 0) atomicAdd(&h[t.w >> GSH], 1);
        ngrp = k + 1;
    }
    __syncthreads();
    // reserve contiguous runs in the bucket-major staging array
    for (int j = tid; j < NB; j += TB1) {
        int c = h[j];
        h[j] = c ? atomicAdd(&cursor[j], c) : 0;
    }
    __syncthreads();
    // pass B: compute w, write packed records into reserved runs
    for (int i = e0 + tid * 4, k = 0; k < ngrp; i += TB1 * 4, ++k) {
        int4 t = d[k];
        int4 ss = make_int4(0, 0, 0, 0);
        float4 ww = make_float4(0.f, 0.f, 0.f, 0.f);
        if (i + 3 < e1) { ss = *(const int4*)(src + i); ww = *(const float4*)(ew + i); }
        else {
            ss.x = src[i]; ww.x = ew[i];
            if (i + 1 < e1) { ss.y = src[i + 1]; ww.y = ew[i + 1]; }
            if (i + 2 < e1) { ss.z = src[i + 2]; ww.z = ew[i + 2]; }
            if (i + 3 < e1) { ss.w = src[i + 3]; ww.w = ew[i + 3]; }
        }
#define PART1(T, S, W) if ((T) >= 0) { \
        float w_ = dis[S] * (W) * dis[T]; \
        int pos_ = atomicAdd(&h[(T) >> GSH], 1); \
        staged[pos_] = make_int2((S) | (((T) & (GB - 1)) << 20), __float_as_int(w_)); }
        PART1(t.x, ss.x, ww.x)
        PART1(t.y, ss.y, ww.y)
        PART1(t.z, ss.z, ww.z)
        PART1(t.w, ss.w, ww.w)
#undef PART1
    }
}

// ---- phase 2: per-bucket placement into final CSR + offsets -------------
// One block owns one bucket: pass 1 counts its 128 nodes' records (LDS),
// serial exclusive scan -> per-node offsets; pass 2 rank-assigns and
// writes csr within a single ~16 KB single-owner region (L2-hot re-read).
__global__ void __launch_bounds__(256)
place_kernel(const int2* __restrict__ staged, const int* __restrict__ bucket_base,
             int* __restrict__ offsets, int2* __restrict__ csr, int N) {
    __shared__ int cnt[GB];
    __shared__ int cur[GB];
    __shared__ int pre[GB + 1];
    const int b = blockIdx.x;
    const int n0 = b << GSH;
    const int nb = min(GB, N - n0);
    const int r0 = bucket_base[b], r1 = bucket_base[b + 1];
    for (int j = threadIdx.x; j < GB; j += 256) cnt[j] = 0;
    __syncthreads();
    for (int i = r0 + threadIdx.x; i < r1; i += 256)
        atomicAdd(&cnt[(staged[i].x >> 20) & (GB - 1)], 1);
    __syncthreads();
    if (threadIdx.x == 0) {
        int run = r0;
        for (int j = 0; j < nb; ++j) { pre[j] = run; run += cnt[j]; }
        pre[nb] = run;
    }
    __syncthreads();
    for (int j = threadIdx.x; j < nb; j += 256) { offsets[n0 + j] = pre[j]; cur[j] = pre[j]; }
    __syncthreads();
    for (int i = r0 + threadIdx.x; i < r1; i += 256) {
        int2 rec = staged[i];
        int tl = (rec.x >> 20) & (GB - 1);
        int rank = atomicAdd(&cur[tl], 1);
        csr[rank] = make_int2(rec.x & 0xFFFFF, rec.y);
    }
}

// fp32 emb -> bf16 copy (one uint4 = 8 bf16 per thread)
__global__ void __launch_bounds__(256)
conv_kernel(const float4* __restrict__ in4, uint4* __restrict__ outb, int n8) {
    int i = blockIdx.x * blockDim.x + threadIdx.x;
    if (i >= n8) return;
    float4 a = in4[2 * i], b = in4[2 * i + 1];
    uint4 o;
    o.x = pack2(a.x, a.y); o.y = pack2(a.z, a.w);
    o.z = pack2(b.x, b.y); o.w = pack2(b.z, b.w);
    outb[i] = o;
}

// ---- propagation (unchanged) --------------------------------------------
// 8 nodes per wave: lane = (sub = lane>>3 -> node, fl = lane&7 -> 16B chunk
// = 8 bf16 of the 128B bf16 row). x8 unroll -> 64 row-gathers in flight.
__global__ void __launch_bounds__(256)
prop_kernel(const uint4* __restrict__ xg, const float4* __restrict__ selfF,
            uint4* __restrict__ xstore,
            const int* __restrict__ offsets, const int2* __restrict__ csr,
            const float* __restrict__ dis, int n) {
    const int lane = threadIdx.x & 63;
    const int fl  = lane & 7;
    const int sub = lane >> 3;
    const int wave = blockIdx.x * (blockDim.x >> 6) + (threadIdx.x >> 6);
    const int node = wave * 8 + sub;
    if (node >= n) return;

    const int beg = offsets[node];
    const int end = offsets[node + 1];
    const float d = dis[node];
    const float dd = d * d;   // self-loop: norm = dis[i]^2, weight 1

    float a0, a1, a2, a3, a4, a5, a6, a7;
    if (selfF) {
        float4 s0 = selfF[node * 16 + fl * 2];
        float4 s1 = selfF[node * 16 + fl * 2 + 1];
        a0 = dd * s0.x; a1 = dd * s0.y; a2 = dd * s0.z; a3 = dd * s0.w;
        a4 = dd * s1.x; a5 = dd * s1.y; a6 = dd * s1.z; a7 = dd * s1.w;
    } else {
        uint4 q = xg[(size_t)node * 8 + fl];
        float l, h;
        UNPK(q.x, l, h) a0 = dd * l; a1 = dd * h;
        UNPK(q.y, l, h) a2 = dd * l; a3 = dd * h;
        UNPK(q.z, l, h) a4 = dd * l; a5 = dd * h;
        UNPK(q.w, l, h) a6 = dd * l; a7 = dd * h;
    }

#define EDGE(E, Q) { float w_ = __int_as_float((E).y); float l, h; \
    UNPK((Q).x, l, h) a0 = fmaf(w_, l, a0); a1 = fmaf(w_, h, a1); \
    UNPK((Q).y, l, h) a2 = fmaf(w_, l, a2); a3 = fmaf(w_, h, a3); \
    UNPK((Q).z, l, h) a4 = fmaf(w_, l, a4); a5 = fmaf(w_, h, a5); \
    UNPK((Q).w, l, h) a6 = fmaf(w_, l, a6); a7 = fmaf(w_, h, a7); }

    int p = beg;
    for (; p + 8 <= end; p += 8) {
        int2 e0 = csr[p + 0], e1 = csr[p + 1], e2 = csr[p + 2], e3 = csr[p + 3];
        int2 e4 = csr[p + 4], e5 = csr[p + 5], e6 = csr[p + 6], e7 = csr[p + 7];
        uint4 q0 = xg[(size_t)e0.x * 8 + fl];
        uint4 q1 = xg[(size_t)e1.x * 8 + fl];
        uint4 q2 = xg[(size_t)e2.x * 8 + fl];
        uint4 q3 = xg[(size_t)e3.x * 8 + fl];
        uint4 q4 = xg[(size_t)e4.x * 8 + fl];
        uint4 q5 = xg[(size_t)e5.x * 8 + fl];
        uint4 q6 = xg[(size_t)e6.x * 8 + fl];
        uint4 q7 = xg[(size_t)e7.x * 8 + fl];
        EDGE(e0, q0) EDGE(e1, q1) EDGE(e2, q2) EDGE(e3, q3)
        EDGE(e4, q4) EDGE(e5, q5) EDGE(e6, q6) EDGE(e7, q7)
    }
    for (; p + 4 <= end; p += 4) {
        int2 e0 = csr[p + 0], e1 = csr[p + 1], e2 = csr[p + 2], e3 = csr[p + 3];
        uint4 q0 = xg[(size_t)e0.x * 8 + fl];
        uint4 q1 = xg[(size_t)e1.x * 8 + fl];
        uint4 q2 = xg[(size_t)e2.x * 8 + fl];
        uint4 q3 = xg[(size_t)e3.x * 8 + fl];
        EDGE(e0, q0) EDGE(e1, q1) EDGE(e2, q2) EDGE(e3, q3)
    }
    for (; p < end; ++p) {
        int2 e = csr[p];
        uint4 q = xg[(size_t)e.x * 8 + fl];
        EDGE(e, q)
    }
#undef EDGE

    uint4 o;
    o.x = pack2(a0, a1); o.y = pack2(a2, a3);
    o.z = pack2(a4, a5); o.w = pack2(a6, a7);
    xstore[(size_t)node * 8 + fl] = o;
}

// out = 0.25 * (emb + xa + xb + xc), pure streaming.
__global__ void __launch_bounds__(256)
combine_kernel(const float4* __restrict__ emb4, const uint4* __restrict__ xa,
               const uint4* __restrict__ xb, const uint4* __restrict__ xc,
               float4* __restrict__ out4, int n8) {
    int i = blockIdx.x * blockDim.x + threadIdx.x;
    if (i >= n8) return;
    float4 e0 = emb4[2 * i], e1 = emb4[2 * i + 1];
    uint4 qa = xa[i], qb = xb[i], qc = xc[i];
    float r[8] = { e0.x, e0.y, e0.z, e0.w, e1.x, e1.y, e1.z, e1.w };
    float l, h;
    UNPK(qa.x, l, h) r[0] += l; r[1] += h;
    UNPK(qa.y, l, h) r[2] += l; r[3] += h;
    UNPK(qa.z, l, h) r[4] += l; r[5] += h;
    UNPK(qa.w, l, h) r[6] += l; r[7] += h;
    UNPK(qb.x, l, h) r[0] += l; r[1] += h;
    UNPK(qb.y, l, h) r[2] += l; r[3] += h;
    UNPK(qb.z, l, h) r[4] += l; r[5] += h;
    UNPK(qb.w, l, h) r[6] += l; r[7] += h;
    UNPK(qc.x, l, h) r[0] += l; r[1] += h;
    UNPK(qc.y, l, h) r[2] += l; r[3] += h;
    UNPK(qc.z, l, h) r[4] += l; r[5] += h;
    UNPK(qc.w, l, h) r[6] += l; r[7] += h;
    out4[2 * i]     = make_float4(0.25f * r[0], 0.25f * r[1], 0.25f * r[2], 0.25f * r[3]);
    out4[2 * i + 1] = make_float4(0.25f * r[4], 0.25f * r[5], 0.25f * r[6], 0.25f * r[7]);
}

// ---- launch -------------------------------------------------------------

extern "C" void kernel_launch(void* const* d_in, const int* in_sizes, int n_in,
                              void* d_out, int out_size, void* d_ws, size_t ws_size,
                              hipStream_t stream) {
    const float* emb = (const float*)d_in[0];   // [N, 64] fp32
    const float* ew  = (const float*)d_in[1];   // [E] fp32
    const int*   ei  = (const int*)d_in[2];     // [2, E] int32
    const int E = in_sizes[2] / 2;
    const int N = in_sizes[0] / DIM;
    const int* src = ei;        // edge_index[0] = source j
    const int* dst = ei + E;    // edge_index[1] = target i
    float* out = (float*)d_out;

    const int NB = (N + GB - 1) >> GSH;   // dst buckets (782 @ N=100k)
    const int Es = (E + NSLICE - 1) / NSLICE;

    // workspace (~65 MB). Alias chain on one region (sequentially dead):
    //   partials (hist, dead after merge_dis) -> staged (dead after place)
    //   -> xb (first written in prop L2)
    char* w = (char*)d_ws;
    size_t xSz = ((size_t)N * DIM * 2 + 255) & ~(size_t)255;       // 12.8 MB
    size_t sSz = ((size_t)E * 8 + 255) & ~(size_t)255;             // 12.8 MB
    size_t pSz = ((size_t)NSLICE * N * 2 + 255) & ~(size_t)255;    // 12.8 MB
    size_t uSz = xSz > sSz ? xSz : sSz; if (pSz > uSz) uSz = pSz;
    unsigned short* partials = (unsigned short*)w;
    int2* staged = (int2*)w;
    uint4* xb    = (uint4*)w; w += uSz;
    int2* csr    = (int2*)w; w += sSz;
    uint4* x0c   = (uint4*)w; w += xSz;   // bf16 emb copy
    uint4* xa    = (uint4*)w; w += xSz;   // bf16 layer-1 x
    uint4* xc    = (uint4*)w; w += xSz;   // bf16 layer-3 x
    int* offsets = (int*)w; w += ((size_t)(N + 1) * 4 + 255) & ~(size_t)255;
    float* dis   = (float*)w; w += ((size_t)N * 4 + 255) & ~(size_t)255;
    int* bcnt        = (int*)w; w += 1024 * 4;
    int* bucket_base = (int*)w; w += 1025 * 4;
    int* cursor      = (int*)w; w += 1024 * 4;

    const int TB = 256;
    hipMemsetAsync(bcnt, 0, (size_t)NB * 4, stream);

    hist_src_kernel<<<RANGES * NSLICE, TBH, 0, stream>>>(src, partials, E, N, Es);
    bucket_cnt_kernel<<<256, TB, 0, stream>>>(dst, bcnt, E, NB);
    merge_dis_kernel<<<(N + TB - 1) / TB, TB, 0, stream>>>(partials, dis, N);
    scan_buckets<<<1, 1024, 0, stream>>>(bcnt, bucket_base, cursor, offsets, NB, N);
    part_kernel<<<(E + CH - 1) / CH, TB1, 0, stream>>>(src, dst, ew, dis, cursor,
                                                       staged, E, NB);
    place_kernel<<<NB, TB, 0, stream>>>(staged, bucket_base, offsets, csr, N);

    const int n8 = N * DIM / 8;
    conv_kernel<<<(n8 + TB - 1) / TB, TB, 0, stream>>>((const float4*)emb, x0c, n8);

    // 4 waves/block, 8 nodes/wave -> 32 nodes per block
    dim3 grid((N + 31) / 32), block(TB);
    prop_kernel<<<grid, block, 0, stream>>>(x0c, (const float4*)emb, xa,
                                            offsets, csr, dis, N);
    prop_kernel<<<grid, block, 0, stream>>>(xa, nullptr, xb,
                                            offsets, csr, dis, N);
    prop_kernel<<<grid, block, 0, stream>>>(xb, nullptr, xc,
                                            offsets, csr, dis, N);
    combine_kernel<<<(n8 + TB - 1) / TB, TB, 0, stream>>>((const float4*)emb, xa, xb, xc,
                                                          (float4*)out, n8);
}

// Round 3
// 282.068 us; speedup vs baseline: 1.3528x; 1.0091x over previous
//
#include <hip/hip_runtime.h>
#include <stdint.h>

#define DIM 64
#define GB 128          // nodes per dst-bucket (NB = ceil(N/GB) must be <= 1024)
#define GSH 7
#define CH 8192         // edges per partition block (LDS-sorted)
#define TB1 512
#define BINS2 50000     // hist bins per range (u16-packed: 25000 words = 100 KB LDS)
#define RANGES 2        // ceil(100000 / 50000)
#define NSLICE 64       // edge slices for src hist
#define TBH 1024        // hist block size

// bf16 helpers: RNE pack, shift-unpack
__device__ __forceinline__ unsigned bf16rne(float f) {
    unsigned u = __float_as_uint(f);
    return (u + 0x7FFFu + ((u >> 16) & 1u)) >> 16;
}
__device__ __forceinline__ unsigned pack2(float lo, float hi) {
    return bf16rne(lo) | (bf16rne(hi) << 16);
}
#define UNPK(u, lo, hi) { lo = __uint_as_float((u) << 16); hi = __uint_as_float((u) & 0xFFFF0000u); }

// ---- outdeg histogram (u16-packed LDS) + fused dst-bucket totals --------
__global__ void __launch_bounds__(TBH)
hist_src_kernel(const int* __restrict__ src, const int* __restrict__ dst,
                unsigned short* __restrict__ partials, int* __restrict__ bcnt,
                int E, int N, int Es, int NB) {
    __shared__ unsigned h32[BINS2 / 2];  // 100 KB
    __shared__ int hb[1024];             // dst-bucket counts (r==0 blocks only)
    const int b = blockIdx.x;
    const int r = b / NSLICE, s = b % NSLICE;
    const int base = r * BINS2;
    const int hi = min(base + BINS2, N);
    const int nbw = (hi - base + 1) >> 1;  // words (N, base even)
    for (int j = threadIdx.x; j < nbw; j += TBH) h32[j] = 0;
    if (r == 0) for (int j = threadIdx.x; j < NB; j += TBH) hb[j] = 0;
    __syncthreads();
    const int e0 = s * Es, e1 = min(e0 + Es, E);
    if (r == 0) {
#pragma unroll 4
        for (int i = e0 + threadIdx.x; i < e1; i += TBH) {
            unsigned j = (unsigned)(src[i] - base);
            if (j < (unsigned)BINS2) atomicAdd(&h32[j >> 1], 1u << ((j & 1) * 16));
            atomicAdd(&hb[((unsigned)dst[i]) >> GSH], 1);
        }
    } else {
#pragma unroll 4
        for (int i = e0 + threadIdx.x; i < e1; i += TBH) {
            unsigned j = (unsigned)(src[i] - base);
            if (j < (unsigned)BINS2) atomicAdd(&h32[j >> 1], 1u << ((j & 1) * 16));
        }
    }
    __syncthreads();
    unsigned* part = (unsigned*)(partials + (size_t)s * N + base);
    for (int j = threadIdx.x; j < nbw; j += TBH) part[j] = h32[j];
    if (r == 0)
        for (int j = threadIdx.x; j < NB; j += TBH)
            if (hb[j]) atomicAdd(&bcnt[j], hb[j]);
}

// dis[i] = rsqrt(outdeg + 1)
__global__ void __launch_bounds__(256)
merge_dis_kernel(const unsigned short* __restrict__ partials, float* __restrict__ dis, int N) {
    const int i = blockIdx.x * blockDim.x + threadIdx.x;
    if (i >= N) return;
    int od = 0;
    for (int s = 0; s < NSLICE; ++s) od += partials[(size_t)s * N + i];
    dis[i] = rsqrtf((float)od + 1.0f);
}

// single block: exclusive scan of bucket counts -> bases + write cursors
__global__ void scan_buckets(const int* __restrict__ bcnt, int* __restrict__ bucket_base,
                             int* __restrict__ cursor, int* __restrict__ offsets,
                             int NB, int N) {
    __shared__ int buf[1024];
    const int t = threadIdx.x;
    int v = (t < NB) ? bcnt[t] : 0;
    buf[t] = v;
    __syncthreads();
    for (int off = 1; off < 1024; off <<= 1) {
        int add = (t >= off) ? buf[t - off] : 0;
        __syncthreads();
        buf[t] += add;
        __syncthreads();
    }
    if (t < NB) { bucket_base[t] = buf[t] - v; cursor[t] = buf[t] - v; }
    if (t == NB - 1) { bucket_base[NB] = buf[t]; offsets[N] = buf[t]; }
}

// ---- phase 1: partition edges into dst-bucket-major staging -------------
// LDS-reorder version: records are bucket-sorted in LDS first, then flushed
// so consecutive threads write consecutive global addresses (coalesced runs).
__global__ void __launch_bounds__(TB1)
part_kernel(const int* __restrict__ src, const int* __restrict__ dst,
            const float* __restrict__ ew, const float* __restrict__ dis,
            int* __restrict__ cursor, int2* __restrict__ staged, int E, int NB) {
    __shared__ int2 buf[CH];     // 64 KB bucket-sorted records
    __shared__ int addr[CH];     // 32 KB final global slot per record
    __shared__ int h[1024];      // counts -> local write cursor
    __shared__ int sc[1024];     // inclusive scan -> stable lscan
    __shared__ int gb[1024];     // reserved global run base
    const int tid = threadIdx.x;
    const int e0 = blockIdx.x * CH;
    const int e1 = min(e0 + CH, E);
    const int nrec = e1 - e0;
    for (int j = tid; j < 1024; j += TB1) h[j] = 0;
    __syncthreads();
    // pass A: histogram dst buckets, keep dst values in registers
    int4 d[4];
    int ngrp = 0;
    for (int i = e0 + tid * 4, k = 0; i < e1; i += TB1 * 4, ++k) {
        int4 t;
        if (i + 3 < e1) t = *(const int4*)(dst + i);
        else {
            t.x = dst[i];
            t.y = (i + 1 < e1) ? dst[i + 1] : -1;
            t.z = (i + 2 < e1) ? dst[i + 2] : -1;
            t.w = (i + 3 < e1) ? dst[i + 3] : -1;
        }
        d[k] = t;
        if (t.x >= 0) atomicAdd(&h[t.x >> GSH], 1);
        if (t.y >= 0) atomicAdd(&h[t.y >> GSH], 1);
        if (t.z >= 0) atomicAdd(&h[t.z >> GSH], 1);
        if (t.w >= 0) atomicAdd(&h[t.w >> GSH], 1);
        ngrp = k + 1;
    }
    __syncthreads();
    // inclusive scan of h into sc (1024 entries, 512 threads x 2)
    sc[tid] = h[tid]; sc[tid + 512] = h[tid + 512];
    __syncthreads();
    for (int off = 1; off < 1024; off <<= 1) {
        int a0 = (tid >= off) ? sc[tid - off] : 0;
        int a1 = sc[tid + 512 - off];
        __syncthreads();
        sc[tid] += a0; sc[tid + 512] += a1;
        __syncthreads();
    }
    // reserve global runs; h becomes local cursor, sc becomes stable lscan
    for (int j = tid; j < NB; j += TB1) {
        int c = h[j];
        int ls = sc[j] - c;
        gb[j] = c ? atomicAdd(&cursor[j], c) : 0;
        h[j] = ls;
        sc[j] = ls;
    }
    __syncthreads();
    // pass B: compute w, place record bucket-sorted in LDS + its global slot
    for (int i = e0 + tid * 4, k = 0; k < ngrp; i += TB1 * 4, ++k) {
        int4 t = d[k];
        int4 ss = make_int4(0, 0, 0, 0);
        float4 ww = make_float4(0.f, 0.f, 0.f, 0.f);
        if (i + 3 < e1) { ss = *(const int4*)(src + i); ww = *(const float4*)(ew + i); }
        else {
            ss.x = src[i]; ww.x = ew[i];
            if (i + 1 < e1) { ss.y = src[i + 1]; ww.y = ew[i + 1]; }
            if (i + 2 < e1) { ss.z = src[i + 2]; ww.z = ew[i + 2]; }
            if (i + 3 < e1) { ss.w = src[i + 3]; ww.w = ew[i + 3]; }
        }
#define PART1(T, S, W) if ((T) >= 0) { \
        int b_ = (T) >> GSH; \
        float w_ = dis[S] * (W) * dis[T]; \
        int lp_ = atomicAdd(&h[b_], 1); \
        buf[lp_] = make_int2((S) | (((T) & (GB - 1)) << 20), __float_as_int(w_)); \
        addr[lp_] = gb[b_] + (lp_ - sc[b_]); }
        PART1(t.x, ss.x, ww.x)
        PART1(t.y, ss.y, ww.y)
        PART1(t.z, ss.z, ww.z)
        PART1(t.w, ss.w, ww.w)
#undef PART1
    }
    __syncthreads();
    // flush: consecutive threads -> consecutive addresses within runs
    for (int k = tid; k < nrec; k += TB1)
        staged[addr[k]] = buf[k];
}

// ---- phase 2: per-bucket placement into final CSR + offsets -------------
__global__ void __launch_bounds__(256)
place_kernel(const int2* __restrict__ staged, const int* __restrict__ bucket_base,
             int* __restrict__ offsets, int2* __restrict__ csr, int N) {
    __shared__ int cnt[GB];
    __shared__ int cur[GB];
    __shared__ int pre[GB + 1];
    const int b = blockIdx.x;
    const int n0 = b << GSH;
    const int nb = min(GB, N - n0);
    const int r0 = bucket_base[b], r1 = bucket_base[b + 1];
    for (int j = threadIdx.x; j < GB; j += 256) cnt[j] = 0;
    __syncthreads();
    for (int i = r0 + threadIdx.x; i < r1; i += 256)
        atomicAdd(&cnt[(staged[i].x >> 20) & (GB - 1)], 1);
    __syncthreads();
    if (threadIdx.x == 0) {
        int run = r0;
        for (int j = 0; j < nb; ++j) { pre[j] = run; run += cnt[j]; }
        pre[nb] = run;
    }
    __syncthreads();
    for (int j = threadIdx.x; j < nb; j += 256) { offsets[n0 + j] = pre[j]; cur[j] = pre[j]; }
    __syncthreads();
    for (int i = r0 + threadIdx.x; i < r1; i += 256) {
        int2 rec = staged[i];
        int tl = (rec.x >> 20) & (GB - 1);
        int rank = atomicAdd(&cur[tl], 1);
        csr[rank] = make_int2(rec.x & 0xFFFFF, rec.y);
    }
}

// fp32 emb -> bf16 copy (one uint4 = 8 bf16 per thread)
__global__ void __launch_bounds__(256)
conv_kernel(const float4* __restrict__ in4, uint4* __restrict__ outb, int n8) {
    int i = blockIdx.x * blockDim.x + threadIdx.x;
    if (i >= n8) return;
    float4 a = in4[2 * i], b = in4[2 * i + 1];
    uint4 o;
    o.x = pack2(a.x, a.y); o.y = pack2(a.z, a.w);
    o.z = pack2(b.x, b.y); o.w = pack2(b.z, b.w);
    outb[i] = o;
}

// ---- propagation --------------------------------------------------------
// 8 nodes per wave: sub = lane>>3 -> node, fl = lane&7 -> 16B chunk of the
// 128B bf16 row. Last layer (outF != null) fuses the final combine:
// out = 0.25*(emb + xa + xb + xc) with xc in full-precision registers.
__global__ void __launch_bounds__(256)
prop_kernel(const uint4* __restrict__ xg, const float4* __restrict__ selfF,
            uint4* __restrict__ xstore,
            const int* __restrict__ offsets, const int2* __restrict__ csr,
            const float* __restrict__ dis, int n,
            const float4* __restrict__ embF, const uint4* __restrict__ xaF,
            float4* __restrict__ outF) {
    const int lane = threadIdx.x & 63;
    const int fl  = lane & 7;
    const int sub = lane >> 3;
    const int wave = blockIdx.x * (blockDim.x >> 6) + (threadIdx.x >> 6);
    const int node = wave * 8 + sub;
    if (node >= n) return;

    const int beg = offsets[node];
    const int end = offsets[node + 1];
    const float d = dis[node];
    const float dd = d * d;   // self-loop: norm = dis[i]^2, weight 1

    float a0, a1, a2, a3, a4, a5, a6, a7;
    uint4 qs = make_uint4(0, 0, 0, 0);   // self row (kept for fused combine)
    if (selfF) {
        float4 s0 = selfF[(size_t)node * 16 + fl * 2];
        float4 s1 = selfF[(size_t)node * 16 + fl * 2 + 1];
        a0 = dd * s0.x; a1 = dd * s0.y; a2 = dd * s0.z; a3 = dd * s0.w;
        a4 = dd * s1.x; a5 = dd * s1.y; a6 = dd * s1.z; a7 = dd * s1.w;
    } else {
        qs = xg[(size_t)node * 8 + fl];
        float l, h;
        UNPK(qs.x, l, h) a0 = dd * l; a1 = dd * h;
        UNPK(qs.y, l, h) a2 = dd * l; a3 = dd * h;
        UNPK(qs.z, l, h) a4 = dd * l; a5 = dd * h;
        UNPK(qs.w, l, h) a6 = dd * l; a7 = dd * h;
    }

#define EDGE(E, Q) { float w_ = __int_as_float((E).y); float l, h; \
    UNPK((Q).x, l, h) a0 = fmaf(w_, l, a0); a1 = fmaf(w_, h, a1); \
    UNPK((Q).y, l, h) a2 = fmaf(w_, l, a2); a3 = fmaf(w_, h, a3); \
    UNPK((Q).z, l, h) a4 = fmaf(w_, l, a4); a5 = fmaf(w_, h, a5); \
    UNPK((Q).w, l, h) a6 = fmaf(w_, l, a6); a7 = fmaf(w_, h, a7); }

    int p = beg;
    for (; p + 8 <= end; p += 8) {
        int2 e0 = csr[p + 0], e1 = csr[p + 1], e2 = csr[p + 2], e3 = csr[p + 3];
        int2 e4 = csr[p + 4], e5 = csr[p + 5], e6 = csr[p + 6], e7 = csr[p + 7];
        uint4 q0 = xg[(size_t)e0.x * 8 + fl];
        uint4 q1 = xg[(size_t)e1.x * 8 + fl];
        uint4 q2 = xg[(size_t)e2.x * 8 + fl];
        uint4 q3 = xg[(size_t)e3.x * 8 + fl];
        uint4 q4 = xg[(size_t)e4.x * 8 + fl];
        uint4 q5 = xg[(size_t)e5.x * 8 + fl];
        uint4 q6 = xg[(size_t)e6.x * 8 + fl];
        uint4 q7 = xg[(size_t)e7.x * 8 + fl];
        EDGE(e0, q0) EDGE(e1, q1) EDGE(e2, q2) EDGE(e3, q3)
        EDGE(e4, q4) EDGE(e5, q5) EDGE(e6, q6) EDGE(e7, q7)
    }
    for (; p + 4 <= end; p += 4) {
        int2 e0 = csr[p + 0], e1 = csr[p + 1], e2 = csr[p + 2], e3 = csr[p + 3];
        uint4 q0 = xg[(size_t)e0.x * 8 + fl];
        uint4 q1 = xg[(size_t)e1.x * 8 + fl];
        uint4 q2 = xg[(size_t)e2.x * 8 + fl];
        uint4 q3 = xg[(size_t)e3.x * 8 + fl];
        EDGE(e0, q0) EDGE(e1, q1) EDGE(e2, q2) EDGE(e3, q3)
    }
    for (; p < end; ++p) {
        int2 e = csr[p];
        uint4 q = xg[(size_t)e.x * 8 + fl];
        EDGE(e, q)
    }
#undef EDGE

    if (outF) {
        // fused final combine: out = 0.25*(emb + xa + xb(=qs) + xc(regs))
        float4 eA = embF[(size_t)node * 16 + fl * 2];
        float4 eB = embF[(size_t)node * 16 + fl * 2 + 1];
        uint4 qa = xaF[(size_t)node * 8 + fl];
        float r0 = eA.x + a0, r1 = eA.y + a1, r2 = eA.z + a2, r3 = eA.w + a3;
        float r4 = eB.x + a4, r5 = eB.y + a5, r6 = eB.z + a6, r7 = eB.w + a7;
        float l, h;
        UNPK(qa.x, l, h) r0 += l; r1 += h;
        UNPK(qa.y, l, h) r2 += l; r3 += h;
        UNPK(qa.z, l, h) r4 += l; r5 += h;
        UNPK(qa.w, l, h) r6 += l; r7 += h;
        UNPK(qs.x, l, h) r0 += l; r1 += h;
        UNPK(qs.y, l, h) r2 += l; r3 += h;
        UNPK(qs.z, l, h) r4 += l; r5 += h;
        UNPK(qs.w, l, h) r6 += l; r7 += h;
        outF[(size_t)node * 16 + fl * 2] =
            make_float4(0.25f * r0, 0.25f * r1, 0.25f * r2, 0.25f * r3);
        outF[(size_t)node * 16 + fl * 2 + 1] =
            make_float4(0.25f * r4, 0.25f * r5, 0.25f * r6, 0.25f * r7);
    } else {
        uint4 o;
        o.x = pack2(a0, a1); o.y = pack2(a2, a3);
        o.z = pack2(a4, a5); o.w = pack2(a6, a7);
        xstore[(size_t)node * 8 + fl] = o;
    }
}

// ---- launch -------------------------------------------------------------

extern "C" void kernel_launch(void* const* d_in, const int* in_sizes, int n_in,
                              void* d_out, int out_size, void* d_ws, size_t ws_size,
                              hipStream_t stream) {
    const float* emb = (const float*)d_in[0];   // [N, 64] fp32
    const float* ew  = (const float*)d_in[1];   // [E] fp32
    const int*   ei  = (const int*)d_in[2];     // [2, E] int32
    const int E = in_sizes[2] / 2;
    const int N = in_sizes[0] / DIM;
    const int* src = ei;        // edge_index[0] = source j
    const int* dst = ei + E;    // edge_index[1] = target i
    float* out = (float*)d_out;

    const int NB = (N + GB - 1) >> GSH;   // dst buckets (782 @ N=100k)
    const int Es = (E + NSLICE - 1) / NSLICE;

    // workspace (~52 MB). Alias chain on one region (sequentially dead):
    //   partials (dead after merge_dis) -> staged (dead after place)
    //   -> xb (first written in prop L2)
    char* w = (char*)d_ws;
    size_t xSz = ((size_t)N * DIM * 2 + 255) & ~(size_t)255;       // 12.8 MB
    size_t sSz = ((size_t)E * 8 + 255) & ~(size_t)255;             // 12.8 MB
    size_t pSz = ((size_t)NSLICE * N * 2 + 255) & ~(size_t)255;    // 12.8 MB
    size_t uSz = xSz > sSz ? xSz : sSz; if (pSz > uSz) uSz = pSz;
    unsigned short* partials = (unsigned short*)w;
    int2* staged = (int2*)w;
    uint4* xb    = (uint4*)w; w += uSz;
    int2* csr    = (int2*)w; w += sSz;
    uint4* x0c   = (uint4*)w; w += xSz;   // bf16 emb copy
    uint4* xa    = (uint4*)w; w += xSz;   // bf16 layer-1 x
    int* offsets = (int*)w; w += ((size_t)(N + 1) * 4 + 255) & ~(size_t)255;
    float* dis   = (float*)w; w += ((size_t)N * 4 + 255) & ~(size_t)255;
    int* bcnt        = (int*)w; w += 1024 * 4;
    int* bucket_base = (int*)w; w += 1025 * 4;
    int* cursor      = (int*)w; w += 1024 * 4;

    const int TB = 256;
    hipMemsetAsync(bcnt, 0, (size_t)NB * 4, stream);

    hist_src_kernel<<<RANGES * NSLICE, TBH, 0, stream>>>(src, dst, partials, bcnt,
                                                         E, N, Es, NB);
    merge_dis_kernel<<<(N + TB - 1) / TB, TB, 0, stream>>>(partials, dis, N);
    scan_buckets<<<1, 1024, 0, stream>>>(bcnt, bucket_base, cursor, offsets, NB, N);
    part_kernel<<<(E + CH - 1) / CH, TB1, 0, stream>>>(src, dst, ew, dis, cursor,
                                                       staged, E, NB);
    place_kernel<<<NB, TB, 0, stream>>>(staged, bucket_base, offsets, csr, N);

    const int n8 = N * DIM / 8;
    conv_kernel<<<(n8 + TB - 1) / TB, TB, 0, stream>>>((const float4*)emb, x0c, n8);

    // 4 waves/block, 8 nodes/wave -> 32 nodes per block
    dim3 grid((N + 31) / 32), block(TB);
    prop_kernel<<<grid, block, 0, stream>>>(x0c, (const float4*)emb, xa,
                                            offsets, csr, dis, N,
                                            nullptr, nullptr, nullptr);
    prop_kernel<<<grid, block, 0, stream>>>(xa, nullptr, xb,
                                            offsets, csr, dis, N,
                                            nullptr, nullptr, nullptr);
    prop_kernel<<<grid, block, 0, stream>>>(xb, nullptr, nullptr,
                                            offsets, csr, dis, N,
                                            (const float4*)emb, xa, (float4*)out);
}

// Round 4
// 270.199 us; speedup vs baseline: 1.4122x; 1.0439x over previous
//
#include <hip/hip_runtime.h>
#include <stdint.h>

#define DIM 64
#define GB 128          // nodes per dst-bucket (NB = ceil(N/GB) must be <= 1024)
#define GSH 7
#define CH 4096         // edges per partition block (391 blocks @ E=1.6M)
#define TB1 512
#define BINS2 50000     // hist bins per range (u16-packed: 25000 words = 100 KB LDS)
#define RANGES 2        // ceil(100000 / 50000)
#define NSLICE 64       // edge slices for src hist
#define TBH 1024        // hist block size

// bf16 helpers: RNE pack, shift-unpack
__device__ __forceinline__ unsigned bf16rne(float f) {
    unsigned u = __float_as_uint(f);
    return (u + 0x7FFFu + ((u >> 16) & 1u)) >> 16;
}
__device__ __forceinline__ unsigned pack2(float lo, float hi) {
    return bf16rne(lo) | (bf16rne(hi) << 16);
}
#define UNPK(u, lo, hi) { lo = __uint_as_float((u) << 16); hi = __uint_as_float((u) & 0xFFFF0000u); }

// ---- outdeg histogram (u16-packed LDS) + fused dst-bucket totals --------
__global__ void __launch_bounds__(TBH)
hist_src_kernel(const int* __restrict__ src, const int* __restrict__ dst,
                unsigned short* __restrict__ partials, int* __restrict__ bcnt,
                int E, int N, int Es, int NB) {
    __shared__ unsigned h32[BINS2 / 2];  // 100 KB
    __shared__ int hb[1024];             // dst-bucket counts (r==0 blocks only)
    const int b = blockIdx.x;
    const int r = b / NSLICE, s = b % NSLICE;
    const int base = r * BINS2;
    const int hi = min(base + BINS2, N);
    const int nbw = (hi - base + 1) >> 1;  // words (N, base even)
    for (int j = threadIdx.x; j < nbw; j += TBH) h32[j] = 0;
    if (r == 0) for (int j = threadIdx.x; j < NB; j += TBH) hb[j] = 0;
    __syncthreads();
    const int e0 = s * Es, e1 = min(e0 + Es, E);
    if (r == 0) {
#pragma unroll 4
        for (int i = e0 + threadIdx.x; i < e1; i += TBH) {
            unsigned j = (unsigned)(src[i] - base);
            if (j < (unsigned)BINS2) atomicAdd(&h32[j >> 1], 1u << ((j & 1) * 16));
            atomicAdd(&hb[((unsigned)dst[i]) >> GSH], 1);
        }
    } else {
#pragma unroll 4
        for (int i = e0 + threadIdx.x; i < e1; i += TBH) {
            unsigned j = (unsigned)(src[i] - base);
            if (j < (unsigned)BINS2) atomicAdd(&h32[j >> 1], 1u << ((j & 1) * 16));
        }
    }
    __syncthreads();
    unsigned* part = (unsigned*)(partials + (size_t)s * N + base);
    for (int j = threadIdx.x; j < nbw; j += TBH) part[j] = h32[j];
    if (r == 0)
        for (int j = threadIdx.x; j < NB; j += TBH)
            if (hb[j]) atomicAdd(&bcnt[j], hb[j]);
}

// dis[i] = rsqrt(outdeg + 1)
__global__ void __launch_bounds__(256)
merge_dis_kernel(const unsigned short* __restrict__ partials, float* __restrict__ dis, int N) {
    const int i = blockIdx.x * blockDim.x + threadIdx.x;
    if (i >= N) return;
    int od = 0;
    for (int s = 0; s < NSLICE; ++s) od += partials[(size_t)s * N + i];
    dis[i] = rsqrtf((float)od + 1.0f);
}

// single block: exclusive scan of bucket counts -> bases + write cursors
__global__ void scan_buckets(const int* __restrict__ bcnt, int* __restrict__ bucket_base,
                             int* __restrict__ cursor, int* __restrict__ offsets,
                             int NB, int N) {
    __shared__ int buf[1024];
    const int t = threadIdx.x;
    int v = (t < NB) ? bcnt[t] : 0;
    buf[t] = v;
    __syncthreads();
    for (int off = 1; off < 1024; off <<= 1) {
        int add = (t >= off) ? buf[t - off] : 0;
        __syncthreads();
        buf[t] += add;
        __syncthreads();
    }
    if (t < NB) { bucket_base[t] = buf[t] - v; cursor[t] = buf[t] - v; }
    if (t == NB - 1) { bucket_base[NB] = buf[t]; offsets[N] = buf[t]; }
}

// ---- phase 1: partition edges into dst-bucket-major staging -------------
// Simple high-occupancy version: 4 KB LDS, 391 blocks, raw ew stored
// (weight computed later in place_kernel -> no dis gathers here, no
// dependency on merge_dis). Scattered 8B stores are fine: traffic is
// ~8 us at BW; the old bottleneck was CU starvation, not bytes.
__global__ void __launch_bounds__(TB1)
part_kernel(const int* __restrict__ src, const int* __restrict__ dst,
            const float* __restrict__ ew,
            int* __restrict__ cursor, int2* __restrict__ staged, int E, int NB) {
    __shared__ int h[1024];
    const int tid = threadIdx.x;
    const int e0 = blockIdx.x * CH;
    const int e1 = min(e0 + CH, E);
    for (int j = tid; j < NB; j += TB1) h[j] = 0;
    __syncthreads();
    // pass A: histogram dst buckets, keep dst values in registers
    int4 d[CH / (TB1 * 4)];
    int ngrp = 0;
    for (int i = e0 + tid * 4, k = 0; i < e1; i += TB1 * 4, ++k) {
        int4 t;
        if (i + 3 < e1) t = *(const int4*)(dst + i);
        else {
            t.x = dst[i];
            t.y = (i + 1 < e1) ? dst[i + 1] : -1;
            t.z = (i + 2 < e1) ? dst[i + 2] : -1;
            t.w = (i + 3 < e1) ? dst[i + 3] : -1;
        }
        d[k] = t;
        if (t.x >= 0) atomicAdd(&h[t.x >> GSH], 1);
        if (t.y >= 0) atomicAdd(&h[t.y >> GSH], 1);
        if (t.z >= 0) atomicAdd(&h[t.z >> GSH], 1);
        if (t.w >= 0) atomicAdd(&h[t.w >> GSH], 1);
        ngrp = k + 1;
    }
    __syncthreads();
    // reserve contiguous runs; h becomes the block's global write cursor
    for (int j = tid; j < NB; j += TB1) {
        int c = h[j];
        h[j] = c ? atomicAdd(&cursor[j], c) : 0;
    }
    __syncthreads();
    // pass B: write packed records (src | tlocal<<20, raw ew)
    for (int i = e0 + tid * 4, k = 0; k < ngrp; i += TB1 * 4, ++k) {
        int4 t = d[k];
        int4 ss = make_int4(0, 0, 0, 0);
        float4 ww = make_float4(0.f, 0.f, 0.f, 0.f);
        if (i + 3 < e1) { ss = *(const int4*)(src + i); ww = *(const float4*)(ew + i); }
        else {
            ss.x = src[i]; ww.x = ew[i];
            if (i + 1 < e1) { ss.y = src[i + 1]; ww.y = ew[i + 1]; }
            if (i + 2 < e1) { ss.z = src[i + 2]; ww.z = ew[i + 2]; }
            if (i + 3 < e1) { ss.w = src[i + 3]; ww.w = ew[i + 3]; }
        }
#define PART1(T, S, W) if ((T) >= 0) { \
        int pos_ = atomicAdd(&h[(T) >> GSH], 1); \
        staged[pos_] = make_int2((S) | (((T) & (GB - 1)) << 20), __float_as_int(W)); }
        PART1(t.x, ss.x, ww.x)
        PART1(t.y, ss.y, ww.y)
        PART1(t.z, ss.z, ww.z)
        PART1(t.w, ss.w, ww.w)
#undef PART1
    }
}

// ---- phase 2: per-bucket placement into final CSR + offsets -------------
// One block owns one bucket; computes w = dis[src]*ew*dis[dst] here
// (dis[dst] from LDS, dis[src] random gather into L2-resident 400 KB).
__global__ void __launch_bounds__(256)
place_kernel(const int2* __restrict__ staged, const int* __restrict__ bucket_base,
             const float* __restrict__ dis,
             int* __restrict__ offsets, int2* __restrict__ csr, int N) {
    __shared__ int cnt[GB];
    __shared__ int cur[GB];
    __shared__ int pre[GB + 1];
    __shared__ float disb[GB];
    const int b = blockIdx.x;
    const int n0 = b << GSH;
    const int nb = min(GB, N - n0);
    const int r0 = bucket_base[b], r1 = bucket_base[b + 1];
    for (int j = threadIdx.x; j < GB; j += 256) cnt[j] = 0;
    for (int j = threadIdx.x; j < nb; j += 256) disb[j] = dis[n0 + j];
    __syncthreads();
    for (int i = r0 + threadIdx.x; i < r1; i += 256)
        atomicAdd(&cnt[(staged[i].x >> 20) & (GB - 1)], 1);
    __syncthreads();
    if (threadIdx.x == 0) {
        int run = r0;
        for (int j = 0; j < nb; ++j) { pre[j] = run; run += cnt[j]; }
        pre[nb] = run;
    }
    __syncthreads();
    for (int j = threadIdx.x; j < nb; j += 256) { offsets[n0 + j] = pre[j]; cur[j] = pre[j]; }
    __syncthreads();
    for (int i = r0 + threadIdx.x; i < r1; i += 256) {
        int2 rec = staged[i];
        int tl = (rec.x >> 20) & (GB - 1);
        int s = rec.x & 0xFFFFF;
        int rank = atomicAdd(&cur[tl], 1);
        float w = dis[s] * __int_as_float(rec.y) * disb[tl];
        csr[rank] = make_int2(s, __float_as_int(w));
    }
}

// fp32 emb -> bf16 copy (one uint4 = 8 bf16 per thread)
__global__ void __launch_bounds__(256)
conv_kernel(const float4* __restrict__ in4, uint4* __restrict__ outb, int n8) {
    int i = blockIdx.x * blockDim.x + threadIdx.x;
    if (i >= n8) return;
    float4 a = in4[2 * i], b = in4[2 * i + 1];
    uint4 o;
    o.x = pack2(a.x, a.y); o.y = pack2(a.z, a.w);
    o.z = pack2(b.x, b.y); o.w = pack2(b.z, b.w);
    outb[i] = o;
}

// ---- propagation --------------------------------------------------------
// 8 nodes per wave: sub = lane>>3 -> node, fl = lane&7 -> 16B chunk of the
// 128B bf16 row. Last layer (outF != null) fuses the final combine:
// out = 0.25*(emb + xa + xb + xc) with xc in full-precision registers.
__global__ void __launch_bounds__(256)
prop_kernel(const uint4* __restrict__ xg, const float4* __restrict__ selfF,
            uint4* __restrict__ xstore,
            const int* __restrict__ offsets, const int2* __restrict__ csr,
            const float* __restrict__ dis, int n,
            const float4* __restrict__ embF, const uint4* __restrict__ xaF,
            float4* __restrict__ outF) {
    const int lane = threadIdx.x & 63;
    const int fl  = lane & 7;
    const int sub = lane >> 3;
    const int wave = blockIdx.x * (blockDim.x >> 6) + (threadIdx.x >> 6);
    const int node = wave * 8 + sub;
    if (node >= n) return;

    const int beg = offsets[node];
    const int end = offsets[node + 1];
    const float d = dis[node];
    const float dd = d * d;   // self-loop: norm = dis[i]^2, weight 1

    float a0, a1, a2, a3, a4, a5, a6, a7;
    uint4 qs = make_uint4(0, 0, 0, 0);   // self row (kept for fused combine)
    if (selfF) {
        float4 s0 = selfF[(size_t)node * 16 + fl * 2];
        float4 s1 = selfF[(size_t)node * 16 + fl * 2 + 1];
        a0 = dd * s0.x; a1 = dd * s0.y; a2 = dd * s0.z; a3 = dd * s0.w;
        a4 = dd * s1.x; a5 = dd * s1.y; a6 = dd * s1.z; a7 = dd * s1.w;
    } else {
        qs = xg[(size_t)node * 8 + fl];
        float l, h;
        UNPK(qs.x, l, h) a0 = dd * l; a1 = dd * h;
        UNPK(qs.y, l, h) a2 = dd * l; a3 = dd * h;
        UNPK(qs.z, l, h) a4 = dd * l; a5 = dd * h;
        UNPK(qs.w, l, h) a6 = dd * l; a7 = dd * h;
    }

#define EDGE(E, Q) { float w_ = __int_as_float((E).y); float l, h; \
    UNPK((Q).x, l, h) a0 = fmaf(w_, l, a0); a1 = fmaf(w_, h, a1); \
    UNPK((Q).y, l, h) a2 = fmaf(w_, l, a2); a3 = fmaf(w_, h, a3); \
    UNPK((Q).z, l, h) a4 = fmaf(w_, l, a4); a5 = fmaf(w_, h, a5); \
    UNPK((Q).w, l, h) a6 = fmaf(w_, l, a6); a7 = fmaf(w_, h, a7); }

    int p = beg;
    for (; p + 8 <= end; p += 8) {
        int2 e0 = csr[p + 0], e1 = csr[p + 1], e2 = csr[p + 2], e3 = csr[p + 3];
        int2 e4 = csr[p + 4], e5 = csr[p + 5], e6 = csr[p + 6], e7 = csr[p + 7];
        uint4 q0 = xg[(size_t)e0.x * 8 + fl];
        uint4 q1 = xg[(size_t)e1.x * 8 + fl];
        uint4 q2 = xg[(size_t)e2.x * 8 + fl];
        uint4 q3 = xg[(size_t)e3.x * 8 + fl];
        uint4 q4 = xg[(size_t)e4.x * 8 + fl];
        uint4 q5 = xg[(size_t)e5.x * 8 + fl];
        uint4 q6 = xg[(size_t)e6.x * 8 + fl];
        uint4 q7 = xg[(size_t)e7.x * 8 + fl];
        EDGE(e0, q0) EDGE(e1, q1) EDGE(e2, q2) EDGE(e3, q3)
        EDGE(e4, q4) EDGE(e5, q5) EDGE(e6, q6) EDGE(e7, q7)
    }
    for (; p + 4 <= end; p += 4) {
        int2 e0 = csr[p + 0], e1 = csr[p + 1], e2 = csr[p + 2], e3 = csr[p + 3];
        uint4 q0 = xg[(size_t)e0.x * 8 + fl];
        uint4 q1 = xg[(size_t)e1.x * 8 + fl];
        uint4 q2 = xg[(size_t)e2.x * 8 + fl];
        uint4 q3 = xg[(size_t)e3.x * 8 + fl];
        EDGE(e0, q0) EDGE(e1, q1) EDGE(e2, q2) EDGE(e3, q3)
    }
    for (; p < end; ++p) {
        int2 e = csr[p];
        uint4 q = xg[(size_t)e.x * 8 + fl];
        EDGE(e, q)
    }
#undef EDGE

    if (outF) {
        // fused final combine: out = 0.25*(emb + xa + xb(=qs) + xc(regs))
        float4 eA = embF[(size_t)node * 16 + fl * 2];
        float4 eB = embF[(size_t)node * 16 + fl * 2 + 1];
        uint4 qa = xaF[(size_t)node * 8 + fl];
        float r0 = eA.x + a0, r1 = eA.y + a1, r2 = eA.z + a2, r3 = eA.w + a3;
        float r4 = eB.x + a4, r5 = eB.y + a5, r6 = eB.z + a6, r7 = eB.w + a7;
        float l, h;
        UNPK(qa.x, l, h) r0 += l; r1 += h;
        UNPK(qa.y, l, h) r2 += l; r3 += h;
        UNPK(qa.z, l, h) r4 += l; r5 += h;
        UNPK(qa.w, l, h) r6 += l; r7 += h;
        UNPK(qs.x, l, h) r0 += l; r1 += h;
        UNPK(qs.y, l, h) r2 += l; r3 += h;
        UNPK(qs.z, l, h) r4 += l; r5 += h;
        UNPK(qs.w, l, h) r6 += l; r7 += h;
        outF[(size_t)node * 16 + fl * 2] =
            make_float4(0.25f * r0, 0.25f * r1, 0.25f * r2, 0.25f * r3);
        outF[(size_t)node * 16 + fl * 2 + 1] =
            make_float4(0.25f * r4, 0.25f * r5, 0.25f * r6, 0.25f * r7);
    } else {
        uint4 o;
        o.x = pack2(a0, a1); o.y = pack2(a2, a3);
        o.z = pack2(a4, a5); o.w = pack2(a6, a7);
        xstore[(size_t)node * 8 + fl] = o;
    }
}

// ---- launch -------------------------------------------------------------

extern "C" void kernel_launch(void* const* d_in, const int* in_sizes, int n_in,
                              void* d_out, int out_size, void* d_ws, size_t ws_size,
                              hipStream_t stream) {
    const float* emb = (const float*)d_in[0];   // [N, 64] fp32
    const float* ew  = (const float*)d_in[1];   // [E] fp32
    const int*   ei  = (const int*)d_in[2];     // [2, E] int32
    const int E = in_sizes[2] / 2;
    const int N = in_sizes[0] / DIM;
    const int* src = ei;        // edge_index[0] = source j
    const int* dst = ei + E;    // edge_index[1] = target i
    float* out = (float*)d_out;

    const int NB = (N + GB - 1) >> GSH;   // dst buckets (782 @ N=100k)
    const int Es = (E + NSLICE - 1) / NSLICE;

    // workspace (~52 MB). Alias chain on one region (sequentially dead):
    //   partials (dead after merge_dis) -> staged (dead after place)
    //   -> xb (first written in prop L2)
    char* w = (char*)d_ws;
    size_t xSz = ((size_t)N * DIM * 2 + 255) & ~(size_t)255;       // 12.8 MB
    size_t sSz = ((size_t)E * 8 + 255) & ~(size_t)255;             // 12.8 MB
    size_t pSz = ((size_t)NSLICE * N * 2 + 255) & ~(size_t)255;    // 12.8 MB
    size_t uSz = xSz > sSz ? xSz : sSz; if (pSz > uSz) uSz = pSz;
    unsigned short* partials = (unsigned short*)w;
    int2* staged = (int2*)w;
    uint4* xb    = (uint4*)w; w += uSz;
    int2* csr    = (int2*)w; w += sSz;
    uint4* x0c   = (uint4*)w; w += xSz;   // bf16 emb copy
    uint4* xa    = (uint4*)w; w += xSz;   // bf16 layer-1 x
    int* offsets = (int*)w; w += ((size_t)(N + 1) * 4 + 255) & ~(size_t)255;
    float* dis   = (float*)w; w += ((size_t)N * 4 + 255) & ~(size_t)255;
    int* bcnt        = (int*)w; w += 1024 * 4;
    int* bucket_base = (int*)w; w += 1025 * 4;
    int* cursor      = (int*)w; w += 1024 * 4;

    const int TB = 256;
    hipMemsetAsync(bcnt, 0, (size_t)NB * 4, stream);

    hist_src_kernel<<<RANGES * NSLICE, TBH, 0, stream>>>(src, dst, partials, bcnt,
                                                         E, N, Es, NB);
    merge_dis_kernel<<<(N + TB - 1) / TB, TB, 0, stream>>>(partials, dis, N);
    scan_buckets<<<1, 1024, 0, stream>>>(bcnt, bucket_base, cursor, offsets, NB, N);
    part_kernel<<<(E + CH - 1) / CH, TB1, 0, stream>>>(src, dst, ew, cursor,
                                                       staged, E, NB);
    place_kernel<<<NB, TB, 0, stream>>>(staged, bucket_base, dis, offsets, csr, N);

    const int n8 = N * DIM / 8;
    conv_kernel<<<(n8 + TB - 1) / TB, TB, 0, stream>>>((const float4*)emb, x0c, n8);

    // 4 waves/block, 8 nodes/wave -> 32 nodes per block
    dim3 grid((N + 31) / 32), block(TB);
    prop_kernel<<<grid, block, 0, stream>>>(x0c, (const float4*)emb, xa,
                                            offsets, csr, dis, N,
                                            nullptr, nullptr, nullptr);
    prop_kernel<<<grid, block, 0, stream>>>(xa, nullptr, xb,
                                            offsets, csr, dis, N,
                                            nullptr, nullptr, nullptr);
    prop_kernel<<<grid, block, 0, stream>>>(xb, nullptr, nullptr,
                                            offsets, csr, dis, N,
                                            (const float4*)emb, xa, (float4*)out);
}